// Round 6
// baseline (1026.256 us; speedup 1.0000x reference)
//
#include <hip/hip_runtime.h>
#include <hip/hip_cooperative_groups.h>

namespace cg = cooperative_groups;

#define V_NUM 100000
#define E_NUM 50000
#define N_PAIRS 600000
#define DIM 128
#define SCAN_BLK 1024
#define N_SCAN_BLOCKS ((V_NUM + SCAN_BLK - 1) / SCAN_BLK)  // 98
#define NTHREADS 256

// ================= Fused single-dispatch cooperative kernel =================
// Phases (separated by grid.sync):
//  0: zero counts+cursor   1: scores (wave/row)   2: histogram
//  3a: per-1024 scan       3b: scan of 98 block totals (block 0)
//  4: scatter pairs -> CSR (packed int2 {e, exp_bits})
//  5: per-vertex aggregate, lane-parallel CSR entry load + shfl-broadcast
__global__ __launch_bounds__(NTHREADS, 4)
void fused_kernel(const float* __restrict__ v_fea, const float* __restrict__ t_fea,
                  const float* __restrict__ e_fea, const float* __restrict__ a_v,
                  const float* __restrict__ a_t, const float* __restrict__ a_e,
                  const int* __restrict__ ve, float* __restrict__ out,
                  float* __restrict__ s_vt, float* __restrict__ s_e,
                  int* __restrict__ counts, int* __restrict__ cursor,
                  int* __restrict__ blk_scan, int* __restrict__ aux_scan,
                  int2* __restrict__ csr) {
    cg::grid_group grid = cg::this_grid();
    __shared__ int sdata[NTHREADS];

    const int tid = (int)(blockIdx.x * blockDim.x + threadIdx.x);
    const int nthreads = (int)(gridDim.x * blockDim.x);
    const int lane = (int)(threadIdx.x & 63);
    const int wid = tid >> 6;
    const int nwaves = nthreads >> 6;

    // ---- Phase 0: zero counts + cursor (contiguous 200000 ints) ----
    {
        int4* z = (int4*)counts;  // cursor sits right after counts
        for (int i = tid; i < 50000; i += nthreads) z[i] = make_int4(0, 0, 0, 0);
    }
    // ---- Phase 1: scores (independent of phase 0) ----
    {
        const float2 wv = ((const float2*)a_v)[lane];
        const float2 wt = ((const float2*)a_t)[lane];
        const float2 we = ((const float2*)a_e)[lane];
        for (int row = wid; row < V_NUM + E_NUM; row += nwaves) {
            float partial;
            if (row < V_NUM) {
                const float2 vv = ((const float2*)(v_fea + (size_t)row * DIM))[lane];
                const float2 tt = ((const float2*)(t_fea + (size_t)row * DIM))[lane];
                partial = vv.x * wv.x + vv.y * wv.y + tt.x * wt.x + tt.y * wt.y;
            } else {
                const int r = row - V_NUM;
                const float2 ee = ((const float2*)(e_fea + (size_t)r * DIM))[lane];
                partial = ee.x * we.x + ee.y * we.y;
            }
            #pragma unroll
            for (int off = 32; off; off >>= 1) partial += __shfl_xor(partial, off, 64);
            if (lane == 0) {
                if (row < V_NUM) s_vt[row] = partial;
                else s_e[row - V_NUM] = partial;
            }
        }
    }
    grid.sync();

    // ---- Phase 2: histogram of v ----
    for (int p = tid; p < N_PAIRS; p += nthreads)
        atomicAdd(&counts[((const int2*)ve)[p].x], 1);
    grid.sync();

    // ---- Phase 3a: per-block exclusive scan of counts (blocks 0..97) ----
    if (blockIdx.x < N_SCAN_BLOCKS) {
        const int t = (int)threadIdx.x;
        const int base = (int)blockIdx.x * SCAN_BLK + t * 4;
        int4 c = make_int4(0, 0, 0, 0);
        if (base + 3 < V_NUM) {
            c = *(const int4*)(counts + base);
        } else {
            if (base + 0 < V_NUM) c.x = counts[base + 0];
            if (base + 1 < V_NUM) c.y = counts[base + 1];
            if (base + 2 < V_NUM) c.z = counts[base + 2];
            if (base + 3 < V_NUM) c.w = counts[base + 3];
        }
        const int s = c.x + c.y + c.z + c.w;
        sdata[t] = s;
        __syncthreads();
        #pragma unroll
        for (int off = 1; off < NTHREADS; off <<= 1) {
            const int val = (t >= off) ? sdata[t - off] : 0;
            __syncthreads();
            sdata[t] += val;
            __syncthreads();
        }
        const int excl = sdata[t] - s;
        if (t == NTHREADS - 1) aux_scan[blockIdx.x] = sdata[NTHREADS - 1];
        const int e0 = excl, e1 = e0 + c.x, e2 = e1 + c.y, e3 = e2 + c.z;
        if (base + 3 < V_NUM) {
            *(int4*)(blk_scan + base) = make_int4(e0, e1, e2, e3);
        } else {
            if (base + 0 < V_NUM) blk_scan[base + 0] = e0;
            if (base + 1 < V_NUM) blk_scan[base + 1] = e1;
            if (base + 2 < V_NUM) blk_scan[base + 2] = e2;
        }
    }
    grid.sync();

    // ---- Phase 3b: exclusive scan of 98 totals (block 0, 256-wide HS) ----
    if (blockIdx.x == 0) {
        const int t = (int)threadIdx.x;
        const int orig = (t < N_SCAN_BLOCKS) ? aux_scan[t] : 0;
        sdata[t] = orig;
        __syncthreads();
        #pragma unroll
        for (int off = 1; off < NTHREADS; off <<= 1) {
            const int val = (t >= off) ? sdata[t - off] : 0;
            __syncthreads();
            sdata[t] += val;
            __syncthreads();
        }
        if (t < N_SCAN_BLOCKS) aux_scan[t] = sdata[t] - orig;
    }
    grid.sync();

    // ---- Phase 4: scatter into CSR (packed {e, exp_bits}) ----
    for (int p = tid; p < N_PAIRS; p += nthreads) {
        const int2 pe = ((const int2*)ve)[p];
        const float a = tanhf(s_vt[pe.x] + s_e[pe.y]) * 2.0f;  // /TAU, TAU=0.5
        const float ex = __expf(a);  // a in (-2,2): safe without max-subtract
        const int pos = blk_scan[pe.x] + aux_scan[pe.x >> 10] + atomicAdd(&cursor[pe.x], 1);
        csr[pos] = make_int2(pe.y, __float_as_int(ex));
    }
    grid.sync();

    // ---- Phase 5: per-vertex softmax-weighted aggregate ----
    for (int v = wid; v < V_NUM; v += nwaves) {
        const int start = blk_scan[v] + aux_scan[v >> 10];
        const int cnt = counts[v];
        float2 acc = make_float2(0.0f, 0.0f);
        float denom = 0.0f;
        for (int base = 0; base < cnt; base += 64) {
            const int m = min(64, cnt - base);
            int2 ent = make_int2(0, 0);
            if (lane < m) ent = csr[start + base + lane];  // coalesced 8B/lane
            // wave-sum of exp values (zeros beyond m)
            float exv = (lane < m) ? __int_as_float(ent.y) : 0.0f;
            #pragma unroll
            for (int off = 32; off; off >>= 1) exv += __shfl_xor(exv, off, 64);
            denom += exv;
            // gathers: addresses from shuffles -> independent, deep pipeline
            for (int i = 0; i < m; ++i) {
                const int e = __shfl(ent.x, i, 64);
                const float w = __int_as_float(__shfl(ent.y, i, 64));
                const float2 ef = ((const float2*)(e_fea + (size_t)e * DIM))[lane];
                acc.x += w * ef.x;
                acc.y += w * ef.y;
            }
        }
        const float inv = (cnt > 0) ? (1.0f / denom) : 0.0f;
        ((float2*)(out + (size_t)v * DIM))[lane] = make_float2(acc.x * inv, acc.y * inv);
    }
}

// ================= Fallback path (round-3 proven kernels) =================
__global__ void scores_kernel(const float* __restrict__ v_fea, const float* __restrict__ t_fea,
                              const float* __restrict__ e_fea, const float* __restrict__ a_v,
                              const float* __restrict__ a_t, const float* __restrict__ a_e,
                              float* __restrict__ s_vt, float* __restrict__ s_e) {
    const int wave = (int)((blockIdx.x * blockDim.x + threadIdx.x) >> 6);
    const int lane = (int)(threadIdx.x & 63);
    if (wave >= V_NUM + E_NUM) return;
    float partial;
    if (wave < V_NUM) {
        const float2 vv = ((const float2*)(v_fea + (size_t)wave * DIM))[lane];
        const float2 tt = ((const float2*)(t_fea + (size_t)wave * DIM))[lane];
        const float2 wv = ((const float2*)a_v)[lane];
        const float2 wt = ((const float2*)a_t)[lane];
        partial = vv.x * wv.x + vv.y * wv.y + tt.x * wt.x + tt.y * wt.y;
    } else {
        const int r = wave - V_NUM;
        const float2 ee = ((const float2*)(e_fea + (size_t)r * DIM))[lane];
        const float2 we = ((const float2*)a_e)[lane];
        partial = ee.x * we.x + ee.y * we.y;
    }
    #pragma unroll
    for (int off = 32; off; off >>= 1) partial += __shfl_xor(partial, off, 64);
    if (lane == 0) {
        if (wave < V_NUM) s_vt[wave] = partial;
        else s_e[wave - V_NUM] = partial;
    }
}

__global__ void pair_hist(const int* __restrict__ ve, int* __restrict__ counts) {
    const int p = (int)(blockIdx.x * blockDim.x + threadIdx.x);
    if (p >= N_PAIRS) return;
    atomicAdd(&counts[((const int2*)ve)[p].x], 1);
}

__global__ void scan_blocks(const int* __restrict__ counts, int* __restrict__ blk_scan,
                            int* __restrict__ aux) {
    __shared__ int sdata[256];
    const int tid = (int)threadIdx.x;
    const int base = (int)blockIdx.x * SCAN_BLK + tid * 4;
    int4 c = make_int4(0, 0, 0, 0);
    if (base + 3 < V_NUM) c = *(const int4*)(counts + base);
    else {
        if (base + 0 < V_NUM) c.x = counts[base + 0];
        if (base + 1 < V_NUM) c.y = counts[base + 1];
        if (base + 2 < V_NUM) c.z = counts[base + 2];
        if (base + 3 < V_NUM) c.w = counts[base + 3];
    }
    const int s = c.x + c.y + c.z + c.w;
    sdata[tid] = s;
    __syncthreads();
    #pragma unroll
    for (int off = 1; off < 256; off <<= 1) {
        const int val = (tid >= off) ? sdata[tid - off] : 0;
        __syncthreads();
        sdata[tid] += val;
        __syncthreads();
    }
    const int excl = sdata[tid] - s;
    if (tid == 255) aux[blockIdx.x] = sdata[255];
    const int e0 = excl, e1 = e0 + c.x, e2 = e1 + c.y, e3 = e2 + c.z;
    if (base + 3 < V_NUM) *(int4*)(blk_scan + base) = make_int4(e0, e1, e2, e3);
    else {
        if (base + 0 < V_NUM) blk_scan[base + 0] = e0;
        if (base + 1 < V_NUM) blk_scan[base + 1] = e1;
        if (base + 2 < V_NUM) blk_scan[base + 2] = e2;
    }
}

__global__ void scan_aux(int* __restrict__ aux) {
    __shared__ int sdata[128];
    const int tid = (int)threadIdx.x;
    const int orig = (tid < N_SCAN_BLOCKS) ? aux[tid] : 0;
    sdata[tid] = orig;
    __syncthreads();
    #pragma unroll
    for (int off = 1; off < 128; off <<= 1) {
        const int val = (tid >= off) ? sdata[tid - off] : 0;
        __syncthreads();
        sdata[tid] += val;
        __syncthreads();
    }
    if (tid < N_SCAN_BLOCKS) aux[tid] = sdata[tid] - orig;
}

__global__ void pair_scatter(const int* __restrict__ ve, const float* __restrict__ s_vt,
                             const float* __restrict__ s_e, const int* __restrict__ blk_scan,
                             const int* __restrict__ aux_scan, int* __restrict__ cursor,
                             int2* __restrict__ csr) {
    const int p = (int)(blockIdx.x * blockDim.x + threadIdx.x);
    if (p >= N_PAIRS) return;
    const int2 pe = ((const int2*)ve)[p];
    const float a = tanhf(s_vt[pe.x] + s_e[pe.y]) * 2.0f;
    const float ex = __expf(a);
    const int pos = blk_scan[pe.x] + aux_scan[pe.x >> 10] + atomicAdd(&cursor[pe.x], 1);
    csr[pos] = make_int2(pe.y, __float_as_int(ex));
}

__global__ void csr_aggregate(const int* __restrict__ counts, const int* __restrict__ blk_scan,
                              const int* __restrict__ aux_scan, const int2* __restrict__ csr,
                              const float* __restrict__ e_fea, float* __restrict__ out) {
    const int v = (int)((blockIdx.x * blockDim.x + threadIdx.x) >> 6);
    const int lane = (int)(threadIdx.x & 63);
    if (v >= V_NUM) return;
    const int start = blk_scan[v] + aux_scan[v >> 10];
    const int cnt = counts[v];
    float2 acc = make_float2(0.0f, 0.0f);
    float denom = 0.0f;
    for (int base = 0; base < cnt; base += 64) {
        const int m = min(64, cnt - base);
        int2 ent = make_int2(0, 0);
        if (lane < m) ent = csr[start + base + lane];
        float exv = (lane < m) ? __int_as_float(ent.y) : 0.0f;
        #pragma unroll
        for (int off = 32; off; off >>= 1) exv += __shfl_xor(exv, off, 64);
        denom += exv;
        for (int i = 0; i < m; ++i) {
            const int e = __shfl(ent.x, i, 64);
            const float w = __int_as_float(__shfl(ent.y, i, 64));
            const float2 ef = ((const float2*)(e_fea + (size_t)e * DIM))[lane];
            acc.x += w * ef.x;
            acc.y += w * ef.y;
        }
    }
    const float inv = (cnt > 0) ? (1.0f / denom) : 0.0f;
    ((float2*)(out + (size_t)v * DIM))[lane] = make_float2(acc.x * inv, acc.y * inv);
}

extern "C" void kernel_launch(void* const* d_in, const int* in_sizes, int n_in,
                              void* d_out, int out_size, void* d_ws, size_t ws_size,
                              hipStream_t stream) {
    const float* v_fea = (const float*)d_in[0];
    const float* t_fea = (const float*)d_in[1];
    const float* e_fea = (const float*)d_in[2];
    const float* a_v   = (const float*)d_in[3];
    const float* a_t   = (const float*)d_in[4];
    const float* a_e   = (const float*)d_in[5];
    const int*   ve    = (const int*)d_in[6];
    float* out = (float*)d_out;

    // ---- workspace layout (16B aligned) ----
    char* ws = (char*)d_ws;
    float* s_vt     = (float*)(ws + 0);                 // 400,000 B
    float* s_e      = (float*)(ws + 524288);            // 200,000 B
    int*   counts   = (int*)  (ws + 1048576);           // 400,000 B } contiguous for
    int*   cursor   = (int*)  (ws + 1048576 + 400000);  // 400,000 B } one zero pass
    int*   blk_scan = (int*)  (ws + 2097152);           // 400,000 B
    int*   aux_scan = (int*)  (ws + 2097152 + 400000);  // 512 B
    int2*  csr      = (int2*) (ws + 3145728);           // 4,800,000 B

    // co-residency-safe grid for cooperative launch
    int maxBlocksPerCU = 0;
    hipError_t qerr = hipOccupancyMaxActiveBlocksPerMultiprocessor(
        &maxBlocksPerCU, fused_kernel, NTHREADS, 0);
    int grid = (qerr == hipSuccess && maxBlocksPerCU > 0) ? maxBlocksPerCU * 256 : 0;
    if (grid > 2048) grid = 2048;

    bool launched = false;
    if (grid >= N_SCAN_BLOCKS) {
        void* args[] = {(void*)&v_fea, (void*)&t_fea, (void*)&e_fea, (void*)&a_v,
                        (void*)&a_t, (void*)&a_e, (void*)&ve, (void*)&out,
                        (void*)&s_vt, (void*)&s_e, (void*)&counts, (void*)&cursor,
                        (void*)&blk_scan, (void*)&aux_scan, (void*)&csr};
        hipError_t err = hipLaunchCooperativeKernel(fused_kernel, dim3(grid), dim3(NTHREADS),
                                                    args, 0, stream);
        launched = (err == hipSuccess);
    }

    if (!launched) {  // proven multi-kernel fallback
        hipMemsetAsync(counts, 0, 800000, stream);
        {
            const int total_waves = V_NUM + E_NUM;
            scores_kernel<<<(total_waves * 64 + 255) / 256, 256, 0, stream>>>(
                v_fea, t_fea, e_fea, a_v, a_t, a_e, s_vt, s_e);
        }
        pair_hist<<<(N_PAIRS + 255) / 256, 256, 0, stream>>>(ve, counts);
        scan_blocks<<<N_SCAN_BLOCKS, 256, 0, stream>>>(counts, blk_scan, aux_scan);
        scan_aux<<<1, 128, 0, stream>>>(aux_scan);
        pair_scatter<<<(N_PAIRS + 255) / 256, 256, 0, stream>>>(
            ve, s_vt, s_e, blk_scan, aux_scan, cursor, csr);
        {
            const long long total = (long long)V_NUM * 64;
            csr_aggregate<<<(int)((total + 255) / 256), 256, 0, stream>>>(
                counts, blk_scan, aux_scan, csr, e_fea, out);
        }
    }
}

// Round 8
// 442.018 us; speedup vs baseline: 2.3217x; 2.3217x over previous
//
#include <hip/hip_runtime.h>

#define V_NUM 100000
#define E_NUM 50000
#define N_PAIRS 600000
#define DIM 128

#define ZERO_BLOCKS 196          // 196*256 threads, one int4 each = 200704 ints >= 200000
#define DUAL_ROWS 75000          // 50000 V dual-rows + 25000 E dual-rows
#define SCORE_BLOCKS (DUAL_ROWS / 4)  // 4 waves/block, 1 dual-row per wave
#define SCAN_T 1024
#define CHUNK 100                // 1024*100 = 102400 >= 100000

// ---------------- K1: zero counts+cursor AND fused score matvecs ----------------
// Blocks [0, ZERO_BLOCKS): zero the counts+cursor region (harness poisons ws).
// Remaining blocks: one wave per dual-row; lanes 0-31 row 2r, lanes 32-63 row 2r+1;
// each lane loads float4 (16B) -> 512B coalesced per 32-group per matrix.
__global__ __launch_bounds__(256)
void zero_scores(const float* __restrict__ v_fea, const float* __restrict__ t_fea,
                 const float* __restrict__ e_fea, const float* __restrict__ a_v,
                 const float* __restrict__ a_t, const float* __restrict__ a_e,
                 float* __restrict__ s_vt, float* __restrict__ s_e,
                 int4* __restrict__ zero_base) {
    const int bid = (int)blockIdx.x;
    if (bid < ZERO_BLOCKS) {
        const int i = bid * 256 + (int)threadIdx.x;
        if (i < 50000) zero_base[i] = make_int4(0, 0, 0, 0);  // 200000 ints
        return;
    }
    const int wid = (bid - ZERO_BLOCKS) * 4 + ((int)threadIdx.x >> 6);  // 0..74999
    const int half = ((int)threadIdx.x >> 5) & 1;
    const int sub = (int)threadIdx.x & 31;

    float partial;
    int row;
    bool is_v = (wid < 50000);  // wave-uniform
    if (is_v) {
        row = wid * 2 + half;
        const float4 v4 = ((const float4*)(v_fea + (size_t)row * DIM))[sub];
        const float4 t4 = ((const float4*)(t_fea + (size_t)row * DIM))[sub];
        const float4 wv = ((const float4*)a_v)[sub];
        const float4 wt = ((const float4*)a_t)[sub];
        partial = v4.x * wv.x + v4.y * wv.y + v4.z * wv.z + v4.w * wv.w
                + t4.x * wt.x + t4.y * wt.y + t4.z * wt.z + t4.w * wt.w;
    } else {
        row = (wid - 50000) * 2 + half;
        const float4 e4 = ((const float4*)(e_fea + (size_t)row * DIM))[sub];
        const float4 we = ((const float4*)a_e)[sub];
        partial = e4.x * we.x + e4.y * we.y + e4.z * we.z + e4.w * we.w;
    }
    #pragma unroll
    for (int off = 16; off; off >>= 1) partial += __shfl_xor(partial, off, 64);
    if (sub == 0) {
        if (is_v) s_vt[row] = partial;
        else s_e[row] = partial;
    }
}

// ---------------- K2: histogram of v ----------------
__global__ __launch_bounds__(256)
void pair_hist(const int2* __restrict__ ve, int* __restrict__ counts) {
    const int p = (int)(blockIdx.x * blockDim.x + threadIdx.x);
    if (p >= N_PAIRS) return;
    atomicAdd(&counts[ve[p].x], 1);
}

// ---------------- K3: single-workgroup full exclusive scan ----------------
// 1024 threads, 100 contiguous counts each; two passes + LDS Hillis-Steele over
// thread sums. Writes vstart[0..V_NUM] (vstart[V_NUM] = total = N_PAIRS).
__global__ __launch_bounds__(SCAN_T)
void full_scan(const int* __restrict__ counts, int* __restrict__ vstart) {
    __shared__ int sh[SCAN_T];
    const int t = (int)threadIdx.x;
    const int base = t * CHUNK;
    int sum = 0;
    #pragma unroll 4
    for (int k = 0; k < CHUNK; ++k) {
        const int i = base + k;
        if (i < V_NUM) sum += counts[i];
    }
    sh[t] = sum;
    __syncthreads();
    #pragma unroll
    for (int off = 1; off < SCAN_T; off <<= 1) {
        const int val = (t >= off) ? sh[t - off] : 0;
        __syncthreads();
        sh[t] += val;
        __syncthreads();
    }
    int run = sh[t] - sum;  // exclusive offset of this thread's chunk
    #pragma unroll 4
    for (int k = 0; k < CHUNK; ++k) {
        const int i = base + k;
        if (i < V_NUM) {
            const int c = counts[i];
            vstart[i] = run;
            run += c;
        }
    }
    if (t == SCAN_T - 1) vstart[V_NUM] = run;
}

// ---------------- K4: scatter pairs into CSR (packed {e, exp_bits}) ----------------
// a = tanh(s_vt[v]+s_e[e])/0.5 in (-2,2) -> exp safe without max-subtraction
// (w = ex/denom is mathematically identical to the max-shifted form).
__global__ __launch_bounds__(256)
void pair_scatter(const int2* __restrict__ ve, const float* __restrict__ s_vt,
                  const float* __restrict__ s_e, const int* __restrict__ vstart,
                  int* __restrict__ cursor, int2* __restrict__ csr) {
    const int p = (int)(blockIdx.x * blockDim.x + threadIdx.x);
    if (p >= N_PAIRS) return;
    const int2 pe = ve[p];
    const float ex = __expf(2.0f * tanhf(s_vt[pe.x] + s_e[pe.y]));
    const int pos = vstart[pe.x] + atomicAdd(&cursor[pe.x], 1);
    csr[pos] = make_int2(pe.y, __float_as_int(ex));
}

// ---------------- K5: per-vertex softmax-weighted aggregate ----------------
// One wave per vertex, split into two 32-lane groups processing alternate CSR
// entries -> 2 independent gather chains; float4 (16B/lane) e_fea gathers.
// Cross-group combine via 5 shuffles; single coalesced float4 row store.
__global__ __launch_bounds__(256)
void csr_aggregate(const int* __restrict__ vstart, const int2* __restrict__ csr,
                   const float* __restrict__ e_fea, float* __restrict__ out) {
    const int v = (int)((blockIdx.x * blockDim.x + threadIdx.x) >> 6);
    if (v >= V_NUM) return;
    const int half = ((int)threadIdx.x >> 5) & 1;
    const int sub = (int)threadIdx.x & 31;
    const int start = vstart[v];
    const int cnt = vstart[v + 1] - start;

    float4 acc = make_float4(0.0f, 0.0f, 0.0f, 0.0f);
    float den = 0.0f;
    for (int i = half; i < cnt; i += 2) {
        const int2 ent = csr[start + i];       // 32-lane broadcast load
        const float w = __int_as_float(ent.y);
        den += w;
        const float4 ef = ((const float4*)(e_fea + (size_t)ent.x * DIM))[sub];
        acc.x += w * ef.x;
        acc.y += w * ef.y;
        acc.z += w * ef.z;
        acc.w += w * ef.w;
    }
    acc.x += __shfl_xor(acc.x, 32, 64);
    acc.y += __shfl_xor(acc.y, 32, 64);
    acc.z += __shfl_xor(acc.z, 32, 64);
    acc.w += __shfl_xor(acc.w, 32, 64);
    den   += __shfl_xor(den, 32, 64);
    const float inv = (cnt > 0) ? (1.0f / den) : 0.0f;
    if (half == 0)
        ((float4*)(out + (size_t)v * DIM))[sub] =
            make_float4(acc.x * inv, acc.y * inv, acc.z * inv, acc.w * inv);
}

extern "C" void kernel_launch(void* const* d_in, const int* in_sizes, int n_in,
                              void* d_out, int out_size, void* d_ws, size_t ws_size,
                              hipStream_t stream) {
    const float* v_fea = (const float*)d_in[0];
    const float* t_fea = (const float*)d_in[1];
    const float* e_fea = (const float*)d_in[2];
    const float* a_v   = (const float*)d_in[3];
    const float* a_t   = (const float*)d_in[4];
    const float* a_e   = (const float*)d_in[5];
    const int2*  ve    = (const int2*)d_in[6];
    float* out = (float*)d_out;

    // ---- workspace layout (all offsets 16B aligned) ----
    char* ws = (char*)d_ws;
    float* s_vt   = (float*)(ws + 0);                  // 400,000 B
    float* s_e    = (float*)(ws + 524288);             // 200,000 B
    int*   counts = (int*)  (ws + 1048576);            // 400,000 B } contiguous:
    int*   cursor = (int*)  (ws + 1048576 + 400000);   // 400,000 B } zeroed by K1
    int*   vstart = (int*)  (ws + 2097152);            // 400,004 B
    int2*  csr    = (int2*) (ws + 3145728);            // 4,800,000 B

    // K1: zero(counts+cursor) + scores
    zero_scores<<<ZERO_BLOCKS + SCORE_BLOCKS, 256, 0, stream>>>(
        v_fea, t_fea, e_fea, a_v, a_t, a_e, s_vt, s_e, (int4*)counts);
    // K2: histogram
    pair_hist<<<(N_PAIRS + 255) / 256, 256, 0, stream>>>(ve, counts);
    // K3: full exclusive scan (single workgroup)
    full_scan<<<1, SCAN_T, 0, stream>>>(counts, vstart);
    // K4: scatter into CSR
    pair_scatter<<<(N_PAIRS + 255) / 256, 256, 0, stream>>>(
        ve, s_vt, s_e, vstart, cursor, csr);
    // K5: aggregate (writes every out element; no out memset needed)
    {
        const long long total = (long long)V_NUM * 64;
        csr_aggregate<<<(int)((total + 255) / 256), 256, 0, stream>>>(
            vstart, csr, e_fea, out);
    }
}

// Round 10
// 285.968 us; speedup vs baseline: 3.5887x; 1.5457x over previous
//
#include <hip/hip_runtime.h>

#define V_NUM 100000
#define E_NUM 50000
#define N_PAIRS 600000
#define DIM 128

#define ZERO_BLOCKS 196          // 196*256 threads, one int4 each = 200704 ints >= 200000
#define DUAL_ROWS 75000          // 50000 V dual-rows + 25000 E dual-rows
#define SCORE_BLOCKS (DUAL_ROWS / 4)  // 4 waves/block, 1 dual-row per wave
#define N_SCAN_BLOCKS 98         // ceil(100000 / 1024)
#define N_INT4 25000             // V_NUM/4 (exact)

// ---------------- K1: zero counts+cursor AND fused score matvecs ----------------
__global__ __launch_bounds__(256)
void zero_scores(const float* __restrict__ v_fea, const float* __restrict__ t_fea,
                 const float* __restrict__ e_fea, const float* __restrict__ a_v,
                 const float* __restrict__ a_t, const float* __restrict__ a_e,
                 float* __restrict__ s_vt, float* __restrict__ s_e,
                 int4* __restrict__ zero_base) {
    const int bid = (int)blockIdx.x;
    if (bid < ZERO_BLOCKS) {
        const int i = bid * 256 + (int)threadIdx.x;
        if (i < 50000) zero_base[i] = make_int4(0, 0, 0, 0);  // 200000 ints
        return;
    }
    const int wid = (bid - ZERO_BLOCKS) * 4 + ((int)threadIdx.x >> 6);  // 0..74999
    const int half = ((int)threadIdx.x >> 5) & 1;
    const int sub = (int)threadIdx.x & 31;

    float partial;
    int row;
    bool is_v = (wid < 50000);  // wave-uniform
    if (is_v) {
        row = wid * 2 + half;
        const float4 v4 = ((const float4*)(v_fea + (size_t)row * DIM))[sub];
        const float4 t4 = ((const float4*)(t_fea + (size_t)row * DIM))[sub];
        const float4 wv = ((const float4*)a_v)[sub];
        const float4 wt = ((const float4*)a_t)[sub];
        partial = v4.x * wv.x + v4.y * wv.y + v4.z * wv.z + v4.w * wv.w
                + t4.x * wt.x + t4.y * wt.y + t4.z * wt.z + t4.w * wt.w;
    } else {
        row = (wid - 50000) * 2 + half;
        const float4 e4 = ((const float4*)(e_fea + (size_t)row * DIM))[sub];
        const float4 we = ((const float4*)a_e)[sub];
        partial = e4.x * we.x + e4.y * we.y + e4.z * we.z + e4.w * we.w;
    }
    #pragma unroll
    for (int off = 16; off; off >>= 1) partial += __shfl_xor(partial, off, 64);
    if (sub == 0) {
        if (is_v) s_vt[row] = partial;
        else s_e[row] = partial;
    }
}

// ---------------- K2: histogram of v ----------------
__global__ __launch_bounds__(256)
void pair_hist(const int2* __restrict__ ve, int* __restrict__ counts) {
    const int p = (int)(blockIdx.x * blockDim.x + threadIdx.x);
    if (p >= N_PAIRS) return;
    atomicAdd(&counts[ve[p].x], 1);
}

// ---------------- K3: one-dispatch redundant scan ----------------
// 98 blocks; block b re-reads counts[0 .. b*1024) coalesced (int4, L2-resident,
// ~20MB total redundant traffic) -> sum_before; then scans its own 1024-chunk in
// LDS and writes vstart directly. Zero inter-block communication.
__global__ __launch_bounds__(256)
void scan98(const int* __restrict__ counts, int* __restrict__ vstart) {
    __shared__ int red[256];
    __shared__ int sh[256];
    const int t = (int)threadIdx.x;
    const int b = (int)blockIdx.x;
    const int4* c4 = (const int4*)counts;

    // Phase A: sum of all counts before this block's chunk (coalesced)
    int pa = 0;
    for (int i = t; i < b * 256; i += 256) {
        const int4 c = c4[i];
        pa += c.x + c.y + c.z + c.w;
    }
    red[t] = pa;
    __syncthreads();
    #pragma unroll
    for (int off = 128; off; off >>= 1) {
        if (t < off) red[t] += red[t + off];
        __syncthreads();
    }
    const int sum_before = red[0];

    // Phase B: exclusive scan of own 1024-chunk
    const int i4 = b * 256 + t;
    int4 c = make_int4(0, 0, 0, 0);
    if (i4 < N_INT4) c = c4[i4];
    const int s = c.x + c.y + c.z + c.w;
    sh[t] = s;
    __syncthreads();
    #pragma unroll
    for (int off = 1; off < 256; off <<= 1) {
        const int val = (t >= off) ? sh[t - off] : 0;
        __syncthreads();
        sh[t] += val;
        __syncthreads();
    }
    const int e0 = sum_before + sh[t] - s;
    if (i4 < N_INT4)
        ((int4*)vstart)[i4] = make_int4(e0, e0 + c.x, e0 + c.x + c.y, e0 + c.x + c.y + c.z);
    if (b == 0 && t == 0) vstart[V_NUM] = N_PAIRS;
}

// ---------------- K4: scatter pairs into CSR (packed {e, exp_bits}) ----------------
// a = tanh(s_vt[v]+s_e[e])/0.5 in (-2,2) -> exp safe without max-subtraction
// (w = ex/denom is mathematically identical to the max-shifted form).
__global__ __launch_bounds__(256)
void pair_scatter(const int2* __restrict__ ve, const float* __restrict__ s_vt,
                  const float* __restrict__ s_e, const int* __restrict__ vstart,
                  int* __restrict__ cursor, int2* __restrict__ csr) {
    const int p = (int)(blockIdx.x * blockDim.x + threadIdx.x);
    if (p >= N_PAIRS) return;
    const int2 pe = ve[p];
    const float ex = __expf(2.0f * tanhf(s_vt[pe.x] + s_e[pe.y]));
    const int pos = vstart[pe.x] + atomicAdd(&cursor[pe.x], 1);
    csr[pos] = make_int2(pe.y, __float_as_int(ex));
}

// ---------------- K5: per-vertex softmax-weighted aggregate ----------------
// One wave per vertex, two 32-lane groups on alternate CSR entries -> 2
// independent gather chains; float4 (16B/lane) e_fea gathers; combine via
// 5 shuffles; single coalesced float4 row store.
__global__ __launch_bounds__(256)
void csr_aggregate(const int* __restrict__ vstart, const int2* __restrict__ csr,
                   const float* __restrict__ e_fea, float* __restrict__ out) {
    const int v = (int)((blockIdx.x * blockDim.x + threadIdx.x) >> 6);
    if (v >= V_NUM) return;
    const int half = ((int)threadIdx.x >> 5) & 1;
    const int sub = (int)threadIdx.x & 31;
    const int start = vstart[v];
    const int cnt = vstart[v + 1] - start;

    float4 acc = make_float4(0.0f, 0.0f, 0.0f, 0.0f);
    float den = 0.0f;
    for (int i = half; i < cnt; i += 2) {
        const int2 ent = csr[start + i];       // 32-lane broadcast load
        const float w = __int_as_float(ent.y);
        den += w;
        const float4 ef = ((const float4*)(e_fea + (size_t)ent.x * DIM))[sub];
        acc.x += w * ef.x;
        acc.y += w * ef.y;
        acc.z += w * ef.z;
        acc.w += w * ef.w;
    }
    acc.x += __shfl_xor(acc.x, 32, 64);
    acc.y += __shfl_xor(acc.y, 32, 64);
    acc.z += __shfl_xor(acc.z, 32, 64);
    acc.w += __shfl_xor(acc.w, 32, 64);
    den   += __shfl_xor(den, 32, 64);
    const float inv = (cnt > 0) ? (1.0f / den) : 0.0f;
    if (half == 0)
        ((float4*)(out + (size_t)v * DIM))[sub] =
            make_float4(acc.x * inv, acc.y * inv, acc.z * inv, acc.w * inv);
}

extern "C" void kernel_launch(void* const* d_in, const int* in_sizes, int n_in,
                              void* d_out, int out_size, void* d_ws, size_t ws_size,
                              hipStream_t stream) {
    const float* v_fea = (const float*)d_in[0];
    const float* t_fea = (const float*)d_in[1];
    const float* e_fea = (const float*)d_in[2];
    const float* a_v   = (const float*)d_in[3];
    const float* a_t   = (const float*)d_in[4];
    const float* a_e   = (const float*)d_in[5];
    const int2*  ve    = (const int2*)d_in[6];
    float* out = (float*)d_out;

    // ---- workspace layout (all offsets 16B aligned) ----
    char* ws = (char*)d_ws;
    float* s_vt   = (float*)(ws + 0);                  // 400,000 B
    float* s_e    = (float*)(ws + 524288);             // 200,000 B
    int*   counts = (int*)  (ws + 1048576);            // 400,000 B } contiguous:
    int*   cursor = (int*)  (ws + 1048576 + 400000);   // 400,000 B } zeroed by K1
    int*   vstart = (int*)  (ws + 2097152);            // 400,004 B
    int2*  csr    = (int2*) (ws + 3145728);            // 4,800,000 B

    // K1: zero(counts+cursor) + scores
    zero_scores<<<ZERO_BLOCKS + SCORE_BLOCKS, 256, 0, stream>>>(
        v_fea, t_fea, e_fea, a_v, a_t, a_e, s_vt, s_e, (int4*)counts);
    // K2: histogram
    pair_hist<<<(N_PAIRS + 255) / 256, 256, 0, stream>>>(ve, counts);
    // K3: redundant one-dispatch scan
    scan98<<<N_SCAN_BLOCKS, 256, 0, stream>>>(counts, vstart);
    // K4: scatter into CSR
    pair_scatter<<<(N_PAIRS + 255) / 256, 256, 0, stream>>>(
        ve, s_vt, s_e, vstart, cursor, csr);
    // K5: aggregate (writes every out element; no out memset needed)
    {
        const long long total = (long long)V_NUM * 64;
        csr_aggregate<<<(int)((total + 255) / 256), 256, 0, stream>>>(
            vstart, csr, e_fea, out);
    }
}